// Round 2
// baseline (191.770 us; speedup 1.0000x reference)
//
#include <hip/hip_runtime.h>
#include <hip/hip_bf16.h>

// ---------- types ----------
typedef __attribute__((ext_vector_type(8))) short short8;      // 8 x bf16 (4 VGPR) MFMA frag
typedef __attribute__((ext_vector_type(4))) float f32x4;       // MFMA accumulator
typedef __attribute__((ext_vector_type(4))) unsigned short u16x4;

// ---------- constants ----------
// B=4, N=1024, C=768, H=12, Dh=64, 3C=2304, scale=(C*H)^-0.5 = 1/96
#define NB 4
#define NN 1024
#define NC 768
#define NH 12
#define TC 2304

// workspace byte offsets
#define OFF_XB   0ul                       // x bf16          4096*768*2  = 6291456
#define OFF_WQ   6291456ul                 // qkv_w bf16      2304*768*2  = 3538944
#define OFF_WMU  (OFF_WQ + 3538944ul)      // mu_w bf16       768*384*2   = 589824
#define OFF_WLS  (OFF_WMU + 589824ul)      // ls_w bf16
#define OFF_QKVB (OFF_WLS + 589824ul)      // qkv bf16        4096*2304*2 = 18874368
#define OFF_VT   (OFF_QKVB + 18874368ul)   // v transposed    48*64*1024*2= 6291456
#define OFF_OUTB (OFF_VT + 6291456ul)      // attn-out bf16   4096*768*2  = 6291456

__device__ __forceinline__ unsigned short f2bf(float f) {
    unsigned int u = __float_as_uint(f);
    u = (u + 0x7FFFu + ((u >> 16) & 1u)) >> 16;
    return (unsigned short)u;
}

__device__ __forceinline__ void gload_lds16(const unsigned short* g, unsigned short* l) {
    __builtin_amdgcn_global_load_lds(
        (const __attribute__((address_space(1))) unsigned int*)g,
        (__attribute__((address_space(3))) unsigned int*)l, 16, 0, 0);
}

// ---------- fused cast f32 -> bf16 for all four inputs (dst regions contiguous in ws) ----------
// float4-unit region sizes: x 786432, qkv_w 442368, mu_w 73728, ls_w 73728  (total 1376256)
__global__ void cast_all(const float* __restrict__ x, const float* __restrict__ qkv_w,
                         const float* __restrict__ mu_w, const float* __restrict__ ls_w,
                         unsigned short* __restrict__ dst) {
    int i = blockIdx.x * blockDim.x + threadIdx.x;   // float4 index
    const float* src; int off;
    if (i < 786432)            { src = x;     off = i; }
    else if (i < 1228800)      { src = qkv_w; off = i - 786432; }
    else if (i < 1302528)      { src = mu_w;  off = i - 1228800; }
    else                       { src = ls_w;  off = i - 1302528; }
    f32x4 v = ((const f32x4*)src)[off];
    u16x4 o;
#pragma unroll
    for (int j = 0; j < 4; ++j) o[j] = f2bf(v[j]);
    ((u16x4*)dst)[i] = o;
}

// ---------- shared GEMM body: C(128x128 tile) = A(MxK) * B(NxK)^T ----------
// EPI=0: bf16 out, no bias.  EPI=1: f32 out + bias[col].
template <int EPI>
__device__ __forceinline__ void gemm_body(
    unsigned short* As, unsigned short* Bs,
    const unsigned short* __restrict__ A, const unsigned short* __restrict__ Bm,
    int K, int lda, int ldb, void* __restrict__ Cout, int ldc,
    const float* __restrict__ bias, int row0, int col0)
{
    const int t = threadIdx.x;
    const int lane = t & 63;
    const int wv = t >> 6;
    const int wm = wv >> 1, wn = wv & 1;
    const int li = lane & 15;
    const int koff = (lane >> 4) * 8;

    f32x4 acc[4][4] = {};

    const int tr = t >> 2;          // 0..63
    const int tc = (t & 3) * 8;     // 0,8,16,24
    const unsigned short* ag = A + (size_t)(row0 + tr) * lda + tc;
    const unsigned short* bg = Bm + (size_t)(col0 + tr) * ldb + tc;

    for (int kt = 0; kt < K; kt += 32) {
        gload_lds16(ag,            As + t * 8);
        gload_lds16(ag + 64 * lda, As + 2048 + t * 8);
        gload_lds16(bg,            Bs + t * 8);
        gload_lds16(bg + 64 * ldb, Bs + 2048 + t * 8);
        ag += 32; bg += 32;
        __syncthreads();   // compiler drains vmcnt(0) before barrier -> LDS valid
        short8 af[4], bf[4];
#pragma unroll
        for (int m = 0; m < 4; ++m)
            af[m] = *(const short8*)&As[(wm * 64 + m * 16 + li) * 32 + koff];
#pragma unroll
        for (int n = 0; n < 4; ++n)
            bf[n] = *(const short8*)&Bs[(wn * 64 + n * 16 + li) * 32 + koff];
#pragma unroll
        for (int m = 0; m < 4; ++m)
#pragma unroll
            for (int n = 0; n < 4; ++n)
                acc[m][n] = __builtin_amdgcn_mfma_f32_16x16x32_bf16(af[m], bf[n], acc[m][n], 0, 0, 0);
        __syncthreads();
    }

    // epilogue: C/D layout col = lane&15, row = (lane>>4)*4 + reg
#pragma unroll
    for (int m = 0; m < 4; ++m) {
        const int row = row0 + wm * 64 + m * 16 + (lane >> 4) * 4;
#pragma unroll
        for (int n = 0; n < 4; ++n) {
            const int col = col0 + wn * 64 + n * 16 + li;
#pragma unroll
            for (int r = 0; r < 4; ++r) {
                if (EPI == 0) {
                    ((unsigned short*)Cout)[(size_t)(row + r) * ldc + col] = f2bf(acc[m][n][r]);
                } else {
                    ((float*)Cout)[(size_t)(row + r) * ldc + col] = acc[m][n][r] + bias[col];
                }
            }
        }
    }
}

// qkv = x @ qkv_w^T  (4096 x 2304, K=768), bf16 out, XCD-swizzled
__global__ __launch_bounds__(256, 2) void gemm_qkv(
    const unsigned short* __restrict__ A, const unsigned short* __restrict__ Bm,
    unsigned short* __restrict__ C)
{
    __shared__ unsigned short As[128 * 32];
    __shared__ unsigned short Bs[128 * 32];
    const int bid = blockIdx.y * gridDim.x + blockIdx.x;
    const int nwg = gridDim.x * gridDim.y;            // 576, %8==0
    const int swz = (bid & 7) * (nwg >> 3) + (bid >> 3);
    const int row0 = (swz / gridDim.x) * 128;
    const int col0 = (swz % gridDim.x) * 128;
    gemm_body<0>(As, Bs, A, Bm, NC, NC, NC, C, TC, nullptr, row0, col0);
}

// mu / logsigma heads in one launch: z=0 -> mu, z=1 -> logsigma (K=384)
__global__ __launch_bounds__(256, 2) void gemm_heads(
    const unsigned short* __restrict__ outb,
    const unsigned short* __restrict__ wmu, const unsigned short* __restrict__ wls,
    const float* __restrict__ mu_b, const float* __restrict__ ls_b,
    float* __restrict__ out_mu, float* __restrict__ out_ls)
{
    __shared__ unsigned short As[128 * 32];
    __shared__ unsigned short Bs[128 * 32];
    const int bid = blockIdx.y * gridDim.x + blockIdx.x;
    const int nwg = gridDim.x * gridDim.y;            // 192, %8==0
    const int swz = (bid & 7) * (nwg >> 3) + (bid >> 3);
    const int row0 = (swz / gridDim.x) * 128;
    const int col0 = (swz % gridDim.x) * 128;
    const int z = blockIdx.z;
    gemm_body<1>(As, Bs, outb + (z ? 384 : 0), z ? wls : wmu, 384, NC, 384,
                 z ? (void*)out_ls : (void*)out_mu, NC, z ? ls_b : mu_b, row0, col0);
}

// ---------- transpose V: qkv_b[(b*N+m)*2304 + 1536 + h*64 + d] -> vt[(bh*64+d)*1024 + m] ----------
__global__ __launch_bounds__(256, 4) void transpose_v(
    const unsigned short* __restrict__ qkvb, unsigned short* __restrict__ vt)
{
    __shared__ unsigned short tile[64][65];
    const int t = threadIdx.x;
    const int bh = blockIdx.y;
    const int b = bh / NH, h = bh % NH;
    const int m0 = blockIdx.x * 64;
#pragma unroll
    for (int i = 0; i < 2; ++i) {
        int lin = i * 256 + t;            // 0..511
        int mr = lin >> 3;                // 0..63
        int dr = (lin & 7) * 8;
        short8 v = *(const short8*)(qkvb + (size_t)(b * NN + m0 + mr) * TC + 1536 + h * 64 + dr);
#pragma unroll
        for (int j = 0; j < 8; ++j) tile[mr][dr + j] = (unsigned short)v[j];
    }
    __syncthreads();
#pragma unroll
    for (int i = 0; i < 2; ++i) {
        int lin = i * 256 + t;
        int dw = lin >> 3;                // 0..63
        int mw = (lin & 7) * 8;
        short8 v;
#pragma unroll
        for (int j = 0; j < 8; ++j) v[j] = (short)tile[mw + j][dw];
        *(short8*)(vt + ((size_t)bh * 64 + dw) * NN + m0 + mw) = v;
    }
}

// ---------- fused attention (swapped QK^T: lane owns one q-row, 4 consecutive m per frag) ----------
// grid (N/16, B*H); block 256 = 4 waves. Wave w covers key cols [w*256, w*256+256).
// attn[n,m] = p*w[m]/sum(p*w),  p = exp(s - rowmax),  s = (q.k)*scale + mask.
__global__ __launch_bounds__(256, 2) void attn_kernel(
    const unsigned short* __restrict__ qkvb, const unsigned short* __restrict__ vt,
    const float* __restrict__ mask, const float* __restrict__ weight,
    float* __restrict__ attn_out, unsigned short* __restrict__ outb)
{
    __shared__ unsigned short P[16][1032];   // bf16 unnormalized p; stride 1032 -> bank-uniform
    __shared__ float red_max[4][16];
    __shared__ float red_sum[4][16];

    const int t = threadIdx.x;
    const int lane = t & 63;
    const int wv = t >> 6;
    const int li = lane & 15;
    const int g = lane >> 4;
    const int koff = g * 8;
    const int bh = blockIdx.y;
    const int b = bh / NH, h = bh % NH;
    const int n0 = blockIdx.x * 16;
    const int cb = wv * 256;

    // ---- q fragment (B-operand): col = li -> n = n0+li, k = koff+j (+32 second k-step)
    const unsigned short* qp = qkvb + (size_t)(b * NN + n0 + li) * TC + h * 64 + koff;
    short8 qf0 = *(const short8*)qp;
    short8 qf1 = *(const short8*)(qp + 32);

    // ---- S^T = K q^T: acc[cf] holds rows m = cb+cf*16+g*4+r, col n = n0+li
    f32x4 acc[16];
#pragma unroll
    for (int cf = 0; cf < 16; ++cf) {
        const unsigned short* kp = qkvb + (size_t)(b * NN + cb + cf * 16 + li) * TC + 768 + h * 64 + koff;
        short8 k0 = *(const short8*)kp;
        short8 k1 = *(const short8*)(kp + 32);
        f32x4 c = {};
        c = __builtin_amdgcn_mfma_f32_16x16x32_bf16(k0, qf0, c, 0, 0, 0);
        c = __builtin_amdgcn_mfma_f32_16x16x32_bf16(k1, qf1, c, 0, 0, 0);
        acc[cf] = c;
    }

    // ---- scale + mask (f32x4 loads), row max over this wave's 256 cols
    const float scale = 1.0f / 96.0f;
    const float* mrow = mask + (size_t)b * NN * NN + (size_t)(n0 + li) * NN + cb + g * 4;
    const float* wrow = weight + b * NN + cb + g * 4;
    float rmax = -1e30f;
#pragma unroll
    for (int cf = 0; cf < 16; ++cf) {
        f32x4 m4 = *(const f32x4*)(mrow + cf * 16);
#pragma unroll
        for (int r = 0; r < 4; ++r) {
            float s = acc[cf][r] * scale + m4[r];
            acc[cf][r] = s;
            rmax = fmaxf(rmax, s);
        }
    }
    rmax = fmaxf(rmax, __shfl_xor(rmax, 16, 64));
    rmax = fmaxf(rmax, __shfl_xor(rmax, 32, 64));
    if (lane < 16) red_max[wv][lane] = rmax;
    __syncthreads();
    rmax = fmaxf(fmaxf(red_max[0][li], red_max[1][li]),
                 fmaxf(red_max[2][li], red_max[3][li]));

    // ---- p = exp(s-max)*w; stage bf16 p into LDS (unnormalized); weighted row sum
    float rsum = 0.f;
#pragma unroll
    for (int cf = 0; cf < 16; ++cf) {
        f32x4 w4 = *(const f32x4*)(wrow + cf * 16);
        u16x4 pb;
#pragma unroll
        for (int r = 0; r < 4; ++r) {
            float p = __expf(acc[cf][r] - rmax) * (w4[r] + 1e-10f);
            acc[cf][r] = p;
            rsum += p;
            pb[r] = f2bf(p);
        }
        *(u16x4*)&P[li][cb + cf * 16 + g * 4] = pb;
    }
    rsum += __shfl_xor(rsum, 16, 64);
    rsum += __shfl_xor(rsum, 32, 64);
    if (lane < 16) red_sum[wv][lane] = rsum;
    __syncthreads();   // covers P writes + red_sum
    const float rinv = 1.0f / (red_sum[0][li] + red_sum[1][li]
                             + red_sum[2][li] + red_sum[3][li]);

    // ---- attn store: f32x4 per fragment (lane's own row n0+li)
    float* arow = attn_out + (size_t)bh * NN * NN + (size_t)(n0 + li) * NN + cb + g * 4;
#pragma unroll
    for (int cf = 0; cf < 16; ++cf) {
        f32x4 a4;
#pragma unroll
        for (int r = 0; r < 4; ++r) a4[r] = acc[cf][r] * rinv;
        *(f32x4*)(arow + cf * 16) = a4;
    }

    // ---- PV: out(16 x 64), wave handles 16 d-cols; normalization applied at epilogue
    f32x4 o = {};
    const unsigned short* vp = vt + ((size_t)bh * 64 + wv * 16 + li) * NN + koff;
#pragma unroll
    for (int kt = 0; kt < 32; ++kt) {
        short8 pa = *(const short8*)&P[li][kt * 32 + koff];
        short8 vb = *(const short8*)(vp + kt * 32);
        o = __builtin_amdgcn_mfma_f32_16x16x32_bf16(pa, vb, o, 0, 0, 0);
    }
    const int dcol = h * 64 + wv * 16 + li;
#pragma unroll
    for (int r = 0; r < 4; ++r) {
        const int row = g * 4 + r;
        const float rv = 1.0f / (red_sum[0][row] + red_sum[1][row]
                               + red_sum[2][row] + red_sum[3][row]);
        outb[(size_t)(b * NN + n0 + row) * NC + dcol] = f2bf(o[r] * rv);
    }
}

// ---------- launch ----------
extern "C" void kernel_launch(void* const* d_in, const int* in_sizes, int n_in,
                              void* d_out, int out_size, void* d_ws, size_t ws_size,
                              hipStream_t stream) {
    const float* x      = (const float*)d_in[0];
    const float* mask   = (const float*)d_in[1];
    const float* weight = (const float*)d_in[2];
    const float* qkv_w  = (const float*)d_in[3];
    const float* mu_w   = (const float*)d_in[4];
    const float* mu_b   = (const float*)d_in[5];
    const float* ls_w   = (const float*)d_in[6];
    const float* ls_b   = (const float*)d_in[7];

    char* ws = (char*)d_ws;
    unsigned short* xb   = (unsigned short*)(ws + OFF_XB);
    unsigned short* wq   = (unsigned short*)(ws + OFF_WQ);
    unsigned short* wmu  = (unsigned short*)(ws + OFF_WMU);
    unsigned short* wls  = (unsigned short*)(ws + OFF_WLS);
    unsigned short* qkvb = (unsigned short*)(ws + OFF_QKVB);
    unsigned short* vt   = (unsigned short*)(ws + OFF_VT);
    unsigned short* outb = (unsigned short*)(ws + OFF_OUTB);

    float* out_mu   = (float*)d_out;                 // (4,1024,768)
    float* out_ls   = out_mu + 3145728;              // (4,1024,768)
    float* out_attn = out_mu + 6291456;              // (4,12,1024,1024)

    // one fused cast: 1376256 float4s / 256 = 5376 blocks
    cast_all<<<5376, 256, 0, stream>>>(x, qkv_w, mu_w, ls_w, xb);

    gemm_qkv<<<dim3(TC / 128, 4096 / 128), 256, 0, stream>>>(xb, wq, qkvb);

    transpose_v<<<dim3(NN / 64, NB * NH), 256, 0, stream>>>(qkvb, vt);

    attn_kernel<<<dim3(NN / 16, NB * NH), 256, 0, stream>>>(
        qkvb, vt, mask, weight, out_attn, outb);

    gemm_heads<<<dim3(NC / 128, 4096 / 128, 2), 256, 0, stream>>>(
        outb, wmu, wls, mu_b, ls_b, out_mu, out_ls);
}

// Round 3
// 191.618 us; speedup vs baseline: 1.0008x; 1.0008x over previous
//
#include <hip/hip_runtime.h>
#include <hip/hip_bf16.h>

// ---------- types ----------
typedef __attribute__((ext_vector_type(8))) short short8;      // 8 x bf16 (4 VGPR) MFMA frag
typedef __attribute__((ext_vector_type(4))) float f32x4;       // MFMA accumulator
typedef __attribute__((ext_vector_type(4))) unsigned short u16x4;

// ---------- constants ----------
// B=4, N=1024, C=768, H=12, Dh=64, 3C=2304, scale=(C*H)^-0.5 = 1/96 (96^2 = 9216 = C*H)
#define NB 4
#define NN 1024
#define NC 768
#define NH 12
#define TC 2304

// workspace byte offsets
#define OFF_XB   0ul                       // x bf16          4096*768*2  = 6291456
#define OFF_WQ   6291456ul                 // qkv_w bf16      2304*768*2  = 3538944
#define OFF_WMU  (OFF_WQ + 3538944ul)      // mu_w bf16       768*384*2   = 589824
#define OFF_WLS  (OFF_WMU + 589824ul)      // ls_w bf16
#define OFF_QKVB (OFF_WLS + 589824ul)      // qkv bf16        4096*2304*2 = 18874368
#define OFF_VT   (OFF_QKVB + 18874368ul)   // v transposed    48*64*1024*2= 6291456
#define OFF_OUTB (OFF_VT + 6291456ul)      // attn-out bf16   4096*768*2  = 6291456

__device__ __forceinline__ unsigned short f2bf(float f) {
    unsigned int u = __float_as_uint(f);
    u = (u + 0x7FFFu + ((u >> 16) & 1u)) >> 16;
    return (unsigned short)u;
}

__device__ __forceinline__ void gload_lds16(const unsigned short* g, unsigned short* l) {
    __builtin_amdgcn_global_load_lds(
        (const __attribute__((address_space(1))) unsigned int*)g,
        (__attribute__((address_space(3))) unsigned int*)l, 16, 0, 0);
}

// ---------- fused cast f32 -> bf16 for all four inputs (dst regions contiguous in ws) ----------
// float4-unit region sizes: x 786432, qkv_w 442368, mu_w 73728, ls_w 73728  (total 1376256)
__global__ void cast_all(const float* __restrict__ x, const float* __restrict__ qkv_w,
                         const float* __restrict__ mu_w, const float* __restrict__ ls_w,
                         unsigned short* __restrict__ dst) {
    int i = blockIdx.x * blockDim.x + threadIdx.x;   // float4 index
    const float* src; int off;
    if (i < 786432)            { src = x;     off = i; }
    else if (i < 1228800)      { src = qkv_w; off = i - 786432; }
    else if (i < 1302528)      { src = mu_w;  off = i - 1228800; }
    else                       { src = ls_w;  off = i - 1302528; }
    f32x4 v = ((const f32x4*)src)[off];
    u16x4 o;
#pragma unroll
    for (int j = 0; j < 4; ++j) o[j] = f2bf(v[j]);
    ((u16x4*)dst)[i] = o;
}

// ---------- shared GEMM body: C(128x128 tile) = A(MxK) * B(NxK)^T ----------
// EPI=0: bf16 out, no bias.  EPI=1: f32 out + bias[col].
template <int EPI>
__device__ __forceinline__ void gemm_body(
    unsigned short* As, unsigned short* Bs,
    const unsigned short* __restrict__ A, const unsigned short* __restrict__ Bm,
    int K, int lda, int ldb, void* __restrict__ Cout, int ldc,
    const float* __restrict__ bias, int row0, int col0)
{
    const int t = threadIdx.x;
    const int lane = t & 63;
    const int wv = t >> 6;
    const int wm = wv >> 1, wn = wv & 1;
    const int li = lane & 15;
    const int koff = (lane >> 4) * 8;

    f32x4 acc[4][4] = {};

    const int tr = t >> 2;          // 0..63
    const int tc = (t & 3) * 8;     // 0,8,16,24
    const unsigned short* ag = A + (size_t)(row0 + tr) * lda + tc;
    const unsigned short* bg = Bm + (size_t)(col0 + tr) * ldb + tc;

    for (int kt = 0; kt < K; kt += 32) {
        gload_lds16(ag,            As + t * 8);
        gload_lds16(ag + 64 * lda, As + 2048 + t * 8);
        gload_lds16(bg,            Bs + t * 8);
        gload_lds16(bg + 64 * ldb, Bs + 2048 + t * 8);
        ag += 32; bg += 32;
        __syncthreads();   // compiler drains vmcnt(0) before barrier -> LDS valid
        short8 af[4], bf[4];
#pragma unroll
        for (int m = 0; m < 4; ++m)
            af[m] = *(const short8*)&As[(wm * 64 + m * 16 + li) * 32 + koff];
#pragma unroll
        for (int n = 0; n < 4; ++n)
            bf[n] = *(const short8*)&Bs[(wn * 64 + n * 16 + li) * 32 + koff];
#pragma unroll
        for (int m = 0; m < 4; ++m)
#pragma unroll
            for (int n = 0; n < 4; ++n)
                acc[m][n] = __builtin_amdgcn_mfma_f32_16x16x32_bf16(af[m], bf[n], acc[m][n], 0, 0, 0);
        __syncthreads();
    }

    // epilogue: C/D layout col = lane&15, row = (lane>>4)*4 + reg
#pragma unroll
    for (int m = 0; m < 4; ++m) {
        const int row = row0 + wm * 64 + m * 16 + (lane >> 4) * 4;
#pragma unroll
        for (int n = 0; n < 4; ++n) {
            const int col = col0 + wn * 64 + n * 16 + li;
#pragma unroll
            for (int r = 0; r < 4; ++r) {
                if (EPI == 0) {
                    ((unsigned short*)Cout)[(size_t)(row + r) * ldc + col] = f2bf(acc[m][n][r]);
                } else {
                    ((float*)Cout)[(size_t)(row + r) * ldc + col] = acc[m][n][r] + bias[col];
                }
            }
        }
    }
}

// qkv = x @ qkv_w^T  (4096 x 2304, K=768), bf16 out, XCD-swizzled
__global__ __launch_bounds__(256, 2) void gemm_qkv(
    const unsigned short* __restrict__ A, const unsigned short* __restrict__ Bm,
    unsigned short* __restrict__ C)
{
    __shared__ unsigned short As[128 * 32];
    __shared__ unsigned short Bs[128 * 32];
    const int bid = blockIdx.y * gridDim.x + blockIdx.x;
    const int nwg = gridDim.x * gridDim.y;            // 576, %8==0
    const int swz = (bid & 7) * (nwg >> 3) + (bid >> 3);
    const int row0 = (swz / gridDim.x) * 128;
    const int col0 = (swz % gridDim.x) * 128;
    gemm_body<0>(As, Bs, A, Bm, NC, NC, NC, C, TC, nullptr, row0, col0);
}

// mu / logsigma heads in one launch: z=0 -> mu, z=1 -> logsigma (K=384)
__global__ __launch_bounds__(256, 2) void gemm_heads(
    const unsigned short* __restrict__ outb,
    const unsigned short* __restrict__ wmu, const unsigned short* __restrict__ wls,
    const float* __restrict__ mu_b, const float* __restrict__ ls_b,
    float* __restrict__ out_mu, float* __restrict__ out_ls)
{
    __shared__ unsigned short As[128 * 32];
    __shared__ unsigned short Bs[128 * 32];
    const int bid = blockIdx.y * gridDim.x + blockIdx.x;
    const int nwg = gridDim.x * gridDim.y;            // 192, %8==0
    const int swz = (bid & 7) * (nwg >> 3) + (bid >> 3);
    const int row0 = (swz / gridDim.x) * 128;
    const int col0 = (swz % gridDim.x) * 128;
    const int z = blockIdx.z;
    gemm_body<1>(As, Bs, outb + (z ? 384 : 0), z ? wls : wmu, 384, NC, 384,
                 z ? (void*)out_ls : (void*)out_mu, NC, z ? ls_b : mu_b, row0, col0);
}

// ---------- transpose V: qkv_b[(b*N+m)*2304 + 1536 + h*64 + d] -> vt[(bh*64+d)*1024 + m] ----------
__global__ __launch_bounds__(256, 4) void transpose_v(
    const unsigned short* __restrict__ qkvb, unsigned short* __restrict__ vt)
{
    __shared__ unsigned short tile[64][65];
    const int t = threadIdx.x;
    const int bh = blockIdx.y;
    const int b = bh / NH, h = bh % NH;
    const int m0 = blockIdx.x * 64;
#pragma unroll
    for (int i = 0; i < 2; ++i) {
        int lin = i * 256 + t;            // 0..511
        int mr = lin >> 3;                // 0..63
        int dr = (lin & 7) * 8;
        short8 v = *(const short8*)(qkvb + (size_t)(b * NN + m0 + mr) * TC + 1536 + h * 64 + dr);
#pragma unroll
        for (int j = 0; j < 8; ++j) tile[mr][dr + j] = (unsigned short)v[j];
    }
    __syncthreads();
#pragma unroll
    for (int i = 0; i < 2; ++i) {
        int lin = i * 256 + t;
        int dw = lin >> 3;                // 0..63
        int mw = (lin & 7) * 8;
        short8 v;
#pragma unroll
        for (int j = 0; j < 8; ++j) v[j] = (short)tile[mw + j][dw];
        *(short8*)(vt + ((size_t)bh * 64 + dw) * NN + m0 + mw) = v;
    }
}

// ---------- fused attention, latency-batched ----------
// grid (N/16, B*H); block 256 = 4 waves. Wave w covers key cols [w*256, w*256+256).
// attn[n,m] = p*w[m]/sum(p*w),  p = exp(s - rowmax),  s = (q.k)*scale + mask.
// QK^T: depth-2 double-buffered register batches (8 K-frags + 4 mask f32x4 per chunk);
// mask folded into MFMA C-in (acc_init = mask*96, scale=1/96 exact).
__global__ __launch_bounds__(256, 2) void attn_kernel(
    const unsigned short* __restrict__ qkvb, const unsigned short* __restrict__ vt,
    const float* __restrict__ mask, const float* __restrict__ weight,
    float* __restrict__ attn_out, unsigned short* __restrict__ outb)
{
    __shared__ unsigned short P[16][1032];   // bf16 unnormalized p; stride 1032
    __shared__ float red_max[4][16];
    __shared__ float red_sum[4][16];

    const int t = threadIdx.x;
    const int lane = t & 63;
    const int wv = t >> 6;
    const int li = lane & 15;
    const int g = lane >> 4;
    const int koff = g * 8;
    const int bh = blockIdx.y;
    const int b = bh / NH, h = bh % NH;
    const int n0 = blockIdx.x * 16;
    const int cb = wv * 256;

    // ---- q fragment (B-operand): col = li -> n = n0+li, k = koff+j (+32 second k-step)
    const unsigned short* qp = qkvb + (size_t)(b * NN + n0 + li) * TC + h * 64 + koff;
    short8 qf0 = *(const short8*)qp;
    short8 qf1 = *(const short8*)(qp + 32);

    const unsigned short* kbase = qkvb + (size_t)(b * NN + cb) * TC + 768 + h * 64 + koff;
    const float* mrow = mask + (size_t)b * NN * NN + (size_t)(n0 + li) * NN + cb + g * 4;
    const float* wrow = weight + b * NN + cb + g * 4;

    // ---- S^T = K q^T, chunked 4-cf with depth-2 double buffering
    f32x4 acc[16];
    short8 kA[8], kB[8];
    f32x4 mA[4], mB[4];

    auto load_chunk = [&](int c, short8* kb2, f32x4* mb2) {
#pragma unroll
        for (int j = 0; j < 4; ++j) {
            const unsigned short* kp = kbase + (size_t)((c * 4 + j) * 16 + li) * TC;
            kb2[2 * j]     = *(const short8*)kp;
            kb2[2 * j + 1] = *(const short8*)(kp + 32);
            mb2[j] = *(const f32x4*)(mrow + (c * 4 + j) * 16);
        }
    };
    auto compute_chunk = [&](int c, const short8* kb2, const f32x4* mb2) {
#pragma unroll
        for (int j = 0; j < 4; ++j) {
            f32x4 ci = mb2[j] * 96.0f;     // mask pre-scaled into C-in
            ci = __builtin_amdgcn_mfma_f32_16x16x32_bf16(kb2[2 * j],     qf0, ci, 0, 0, 0);
            ci = __builtin_amdgcn_mfma_f32_16x16x32_bf16(kb2[2 * j + 1], qf1, ci, 0, 0, 0);
            acc[c * 4 + j] = ci;
        }
    };

    load_chunk(0, kA, mA);
    load_chunk(1, kB, mB);
    compute_chunk(0, kA, mA);
    load_chunk(2, kA, mA);
    compute_chunk(1, kB, mB);
    load_chunk(3, kB, mB);
    compute_chunk(2, kA, mA);
    compute_chunk(3, kB, mB);

    // ---- issue all weight loads now (hidden under reduce + barrier)
    f32x4 wb[16];
#pragma unroll
    for (int cf = 0; cf < 16; ++cf) wb[cf] = *(const f32x4*)(wrow + cf * 16);

    // ---- row max over this wave's 256 cols (acc already = s*96; max scales monotonically)
    const float scale = 1.0f / 96.0f;
    float rmax = -1e30f;
#pragma unroll
    for (int cf = 0; cf < 16; ++cf) {
#pragma unroll
        for (int r = 0; r < 4; ++r) rmax = fmaxf(rmax, acc[cf][r]);
    }
    rmax = fmaxf(rmax, __shfl_xor(rmax, 16, 64));
    rmax = fmaxf(rmax, __shfl_xor(rmax, 32, 64));
    if (lane < 16) red_max[wv][lane] = rmax;
    __syncthreads();
    rmax = fmaxf(fmaxf(red_max[0][li], red_max[1][li]),
                 fmaxf(red_max[2][li], red_max[3][li])) * scale;

    // ---- p = exp(s-max)*w; stage bf16 p into LDS (unnormalized); weighted row sum
    float rsum = 0.f;
#pragma unroll
    for (int cf = 0; cf < 16; ++cf) {
        u16x4 pb;
#pragma unroll
        for (int r = 0; r < 4; ++r) {
            float p = __expf(acc[cf][r] * scale - rmax) * (wb[cf][r] + 1e-10f);
            acc[cf][r] = p;
            rsum += p;
            pb[r] = f2bf(p);
        }
        *(u16x4*)&P[li][cb + cf * 16 + g * 4] = pb;
    }
    rsum += __shfl_xor(rsum, 16, 64);
    rsum += __shfl_xor(rsum, 32, 64);
    if (lane < 16) red_sum[wv][lane] = rsum;
    __syncthreads();   // covers P writes + red_sum
    const float rinv = 1.0f / (red_sum[0][li] + red_sum[1][li]
                             + red_sum[2][li] + red_sum[3][li]);

    // ---- attn store: f32x4 per fragment (lane's own row n0+li), fire-and-forget
    float* arow = attn_out + (size_t)bh * NN * NN + (size_t)(n0 + li) * NN + cb + g * 4;
#pragma unroll
    for (int cf = 0; cf < 16; ++cf) {
        f32x4 a4;
#pragma unroll
        for (int r = 0; r < 4; ++r) a4[r] = acc[cf][r] * rinv;
        *(f32x4*)(arow + cf * 16) = a4;
    }

    // ---- PV: out(16 x 64), wave handles 16 d-cols; vt loads depth-2 double-buffered
    f32x4 o = {};
    const unsigned short* vp = vt + ((size_t)bh * 64 + wv * 16 + li) * NN + koff;
    short8 vA[8], vB[8];
    auto vload = [&](int c, short8* vb2) {
#pragma unroll
        for (int j = 0; j < 8; ++j) vb2[j] = *(const short8*)(vp + (c * 8 + j) * 32);
    };
    auto vcomp = [&](int c, const short8* vb2) {
#pragma unroll
        for (int j = 0; j < 8; ++j) {
            short8 pa = *(const short8*)&P[li][(c * 8 + j) * 32 + koff];
            o = __builtin_amdgcn_mfma_f32_16x16x32_bf16(pa, vb2[j], o, 0, 0, 0);
        }
    };
    vload(0, vA);
    vload(1, vB);
    vcomp(0, vA);
    vload(2, vA);
    vcomp(1, vB);
    vload(3, vB);
    vcomp(2, vA);
    vcomp(3, vB);

    const int dcol = h * 64 + wv * 16 + li;
#pragma unroll
    for (int r = 0; r < 4; ++r) {
        const int row = g * 4 + r;
        const float rv = 1.0f / (red_sum[0][row] + red_sum[1][row]
                               + red_sum[2][row] + red_sum[3][row]);
        outb[(size_t)(b * NN + n0 + row) * NC + dcol] = f2bf(o[r] * rv);
    }
}

// ---------- launch ----------
extern "C" void kernel_launch(void* const* d_in, const int* in_sizes, int n_in,
                              void* d_out, int out_size, void* d_ws, size_t ws_size,
                              hipStream_t stream) {
    const float* x      = (const float*)d_in[0];
    const float* mask   = (const float*)d_in[1];
    const float* weight = (const float*)d_in[2];
    const float* qkv_w  = (const float*)d_in[3];
    const float* mu_w   = (const float*)d_in[4];
    const float* mu_b   = (const float*)d_in[5];
    const float* ls_w   = (const float*)d_in[6];
    const float* ls_b   = (const float*)d_in[7];

    char* ws = (char*)d_ws;
    unsigned short* xb   = (unsigned short*)(ws + OFF_XB);
    unsigned short* wq   = (unsigned short*)(ws + OFF_WQ);
    unsigned short* wmu  = (unsigned short*)(ws + OFF_WMU);
    unsigned short* wls  = (unsigned short*)(ws + OFF_WLS);
    unsigned short* qkvb = (unsigned short*)(ws + OFF_QKVB);
    unsigned short* vt   = (unsigned short*)(ws + OFF_VT);
    unsigned short* outb = (unsigned short*)(ws + OFF_OUTB);

    float* out_mu   = (float*)d_out;                 // (4,1024,768)
    float* out_ls   = out_mu + 3145728;              // (4,1024,768)
    float* out_attn = out_mu + 6291456;              // (4,12,1024,1024)

    // one fused cast: 1376256 float4s / 256 = 5376 blocks
    cast_all<<<5376, 256, 0, stream>>>(x, qkv_w, mu_w, ls_w, xb);

    gemm_qkv<<<dim3(TC / 128, 4096 / 128), 256, 0, stream>>>(xb, wq, qkvb);

    transpose_v<<<dim3(NN / 64, NB * NH), 256, 0, stream>>>(qkvb, vt);

    attn_kernel<<<dim3(NN / 16, NB * NH), 256, 0, stream>>>(
        qkvb, vt, mask, weight, out_attn, outb);

    gemm_heads<<<dim3(NC / 128, 4096 / 128, 2), 256, 0, stream>>>(
        outb, wmu, wls, mu_b, ls_b, out_mu, out_ls);
}

// Round 4
// 190.059 us; speedup vs baseline: 1.0090x; 1.0082x over previous
//
#include <hip/hip_runtime.h>
#include <hip/hip_bf16.h>

// ---------- types ----------
typedef __attribute__((ext_vector_type(8))) short short8;      // 8 x bf16 (4 VGPR) MFMA frag
typedef __attribute__((ext_vector_type(4))) float f32x4;       // MFMA accumulator
typedef __attribute__((ext_vector_type(4))) unsigned short u16x4;

// ---------- constants ----------
// B=4, N=1024, C=768, H=12, Dh=64, 3C=2304, scale=(C*H)^-0.5 = 1/96 (96^2 = 9216 = C*H)
#define NB 4
#define NN 1024
#define NC 768
#define NH 12
#define TC 2304

// workspace byte offsets
#define OFF_XB   0ul                       // x bf16          4096*768*2  = 6291456
#define OFF_WQ   6291456ul                 // qkv_w bf16      2304*768*2  = 3538944
#define OFF_WMU  (OFF_WQ + 3538944ul)      // mu_w bf16       768*384*2   = 589824
#define OFF_WLS  (OFF_WMU + 589824ul)      // ls_w bf16
#define OFF_QKVB (OFF_WLS + 589824ul)      // qkv bf16        4096*2304*2 = 18874368
#define OFF_VT   (OFF_QKVB + 18874368ul)   // v transposed    48*64*1024*2= 6291456
#define OFF_OUTB (OFF_VT + 6291456ul)      // attn-out bf16   4096*768*2  = 6291456

__device__ __forceinline__ unsigned short f2bf(float f) {
    unsigned int u = __float_as_uint(f);
    u = (u + 0x7FFFu + ((u >> 16) & 1u)) >> 16;
    return (unsigned short)u;
}

__device__ __forceinline__ void gload_lds16(const unsigned short* g, unsigned short* l) {
    __builtin_amdgcn_global_load_lds(
        (const __attribute__((address_space(1))) unsigned int*)g,
        (__attribute__((address_space(3))) unsigned int*)l, 16, 0, 0);
}

// ---- inline-asm batched loads: volatile asm preserves issue order; compiler can't sink/serialize
__device__ __forceinline__ void gload16(short8& dst, const unsigned short* p) {
    asm volatile("global_load_dwordx4 %0, %1, off" : "=v"(dst) : "v"(p));
}
__device__ __forceinline__ void gloadf4(f32x4& dst, const float* p) {
    asm volatile("global_load_dwordx4 %0, %1, off" : "=v"(dst) : "v"(p));
}
// counted wait + hard scheduler fence (rule #18: sched_barrier after asm waitcnt)
#define WAITV(N) do { asm volatile("s_waitcnt vmcnt(" #N ")" ::: "memory"); \
                      __builtin_amdgcn_sched_barrier(0); } while (0)

// ---------- fused cast f32 -> bf16 for all four inputs (dst regions contiguous in ws) ----------
// float4-unit region sizes: x 786432, qkv_w 442368, mu_w 73728, ls_w 73728  (total 1376256)
__global__ void cast_all(const float* __restrict__ x, const float* __restrict__ qkv_w,
                         const float* __restrict__ mu_w, const float* __restrict__ ls_w,
                         unsigned short* __restrict__ dst) {
    int i = blockIdx.x * blockDim.x + threadIdx.x;   // float4 index
    const float* src; int off;
    if (i < 786432)            { src = x;     off = i; }
    else if (i < 1228800)      { src = qkv_w; off = i - 786432; }
    else if (i < 1302528)      { src = mu_w;  off = i - 1228800; }
    else                       { src = ls_w;  off = i - 1302528; }
    f32x4 v = ((const f32x4*)src)[off];
    u16x4 o;
#pragma unroll
    for (int j = 0; j < 4; ++j) o[j] = f2bf(v[j]);
    ((u16x4*)dst)[i] = o;
}

// ---------- shared GEMM body: C(128x128 tile) = A(MxK) * B(NxK)^T ----------
// EPI=0: bf16 out, no bias.  EPI=1: f32 out + bias[col].
template <int EPI>
__device__ __forceinline__ void gemm_body(
    unsigned short* As, unsigned short* Bs,
    const unsigned short* __restrict__ A, const unsigned short* __restrict__ Bm,
    int K, int lda, int ldb, void* __restrict__ Cout, int ldc,
    const float* __restrict__ bias, int row0, int col0)
{
    const int t = threadIdx.x;
    const int lane = t & 63;
    const int wv = t >> 6;
    const int wm = wv >> 1, wn = wv & 1;
    const int li = lane & 15;
    const int koff = (lane >> 4) * 8;

    f32x4 acc[4][4] = {};

    const int tr = t >> 2;          // 0..63
    const int tc = (t & 3) * 8;     // 0,8,16,24
    const unsigned short* ag = A + (size_t)(row0 + tr) * lda + tc;
    const unsigned short* bg = Bm + (size_t)(col0 + tr) * ldb + tc;

    for (int kt = 0; kt < K; kt += 32) {
        gload_lds16(ag,            As + t * 8);
        gload_lds16(ag + 64 * lda, As + 2048 + t * 8);
        gload_lds16(bg,            Bs + t * 8);
        gload_lds16(bg + 64 * ldb, Bs + 2048 + t * 8);
        ag += 32; bg += 32;
        __syncthreads();   // compiler drains vmcnt(0) before barrier -> LDS valid
        short8 af[4], bf[4];
#pragma unroll
        for (int m = 0; m < 4; ++m)
            af[m] = *(const short8*)&As[(wm * 64 + m * 16 + li) * 32 + koff];
#pragma unroll
        for (int n = 0; n < 4; ++n)
            bf[n] = *(const short8*)&Bs[(wn * 64 + n * 16 + li) * 32 + koff];
#pragma unroll
        for (int m = 0; m < 4; ++m)
#pragma unroll
            for (int n = 0; n < 4; ++n)
                acc[m][n] = __builtin_amdgcn_mfma_f32_16x16x32_bf16(af[m], bf[n], acc[m][n], 0, 0, 0);
        __syncthreads();
    }

    // epilogue: C/D layout col = lane&15, row = (lane>>4)*4 + reg
#pragma unroll
    for (int m = 0; m < 4; ++m) {
        const int row = row0 + wm * 64 + m * 16 + (lane >> 4) * 4;
#pragma unroll
        for (int n = 0; n < 4; ++n) {
            const int col = col0 + wn * 64 + n * 16 + li;
#pragma unroll
            for (int r = 0; r < 4; ++r) {
                if (EPI == 0) {
                    ((unsigned short*)Cout)[(size_t)(row + r) * ldc + col] = f2bf(acc[m][n][r]);
                } else {
                    ((float*)Cout)[(size_t)(row + r) * ldc + col] = acc[m][n][r] + bias[col];
                }
            }
        }
    }
}

// qkv = x @ qkv_w^T  (4096 x 2304, K=768), bf16 out, XCD-swizzled
__global__ __launch_bounds__(256, 2) void gemm_qkv(
    const unsigned short* __restrict__ A, const unsigned short* __restrict__ Bm,
    unsigned short* __restrict__ C)
{
    __shared__ unsigned short As[128 * 32];
    __shared__ unsigned short Bs[128 * 32];
    const int bid = blockIdx.y * gridDim.x + blockIdx.x;
    const int nwg = gridDim.x * gridDim.y;            // 576, %8==0
    const int swz = (bid & 7) * (nwg >> 3) + (bid >> 3);
    const int row0 = (swz / gridDim.x) * 128;
    const int col0 = (swz % gridDim.x) * 128;
    gemm_body<0>(As, Bs, A, Bm, NC, NC, NC, C, TC, nullptr, row0, col0);
}

// mu / logsigma heads in one launch: z=0 -> mu, z=1 -> logsigma (K=384)
__global__ __launch_bounds__(256, 2) void gemm_heads(
    const unsigned short* __restrict__ outb,
    const unsigned short* __restrict__ wmu, const unsigned short* __restrict__ wls,
    const float* __restrict__ mu_b, const float* __restrict__ ls_b,
    float* __restrict__ out_mu, float* __restrict__ out_ls)
{
    __shared__ unsigned short As[128 * 32];
    __shared__ unsigned short Bs[128 * 32];
    const int bid = blockIdx.y * gridDim.x + blockIdx.x;
    const int nwg = gridDim.x * gridDim.y;            // 192, %8==0
    const int swz = (bid & 7) * (nwg >> 3) + (bid >> 3);
    const int row0 = (swz / gridDim.x) * 128;
    const int col0 = (swz % gridDim.x) * 128;
    const int z = blockIdx.z;
    gemm_body<1>(As, Bs, outb + (z ? 384 : 0), z ? wls : wmu, 384, NC, 384,
                 z ? (void*)out_ls : (void*)out_mu, NC, z ? ls_b : mu_b, row0, col0);
}

// ---------- transpose V: qkv_b[(b*N+m)*2304 + 1536 + h*64 + d] -> vt[(bh*64+d)*1024 + m] ----------
__global__ __launch_bounds__(256, 4) void transpose_v(
    const unsigned short* __restrict__ qkvb, unsigned short* __restrict__ vt)
{
    __shared__ unsigned short tile[64][65];
    const int t = threadIdx.x;
    const int bh = blockIdx.y;
    const int b = bh / NH, h = bh % NH;
    const int m0 = blockIdx.x * 64;
#pragma unroll
    for (int i = 0; i < 2; ++i) {
        int lin = i * 256 + t;            // 0..511
        int mr = lin >> 3;                // 0..63
        int dr = (lin & 7) * 8;
        short8 v = *(const short8*)(qkvb + (size_t)(b * NN + m0 + mr) * TC + 1536 + h * 64 + dr);
#pragma unroll
        for (int j = 0; j < 8; ++j) tile[mr][dr + j] = (unsigned short)v[j];
    }
    __syncthreads();
#pragma unroll
    for (int i = 0; i < 2; ++i) {
        int lin = i * 256 + t;
        int dw = lin >> 3;                // 0..63
        int mw = (lin & 7) * 8;
        short8 v;
#pragma unroll
        for (int j = 0; j < 8; ++j) v[j] = (short)tile[mw + j][dw];
        *(short8*)(vt + ((size_t)bh * 64 + dw) * NN + m0 + mw) = v;
    }
}

// ---------- fused attention, asm-forced batched loads (counted vmcnt pipeline) ----------
// grid (N/16, B*H); block 256 = 4 waves. Wave w covers key cols [w*256, w*256+256).
// attn[n,m] = p*w[m]/sum(p*w),  p = exp(s - rowmax),  s = (q.k)*scale + mask.
// Issue order (vmcnt FIFO): qf(2), c0(12), c1(12) | W(12) | c2(12) | W(28->c1) wrong..
// actual counted schedule documented inline.
__global__ __launch_bounds__(256, 2) void attn_kernel(
    const unsigned short* __restrict__ qkvb, const unsigned short* __restrict__ vt,
    const float* __restrict__ mask, const float* __restrict__ weight,
    float* __restrict__ attn_out, unsigned short* __restrict__ outb)
{
    __shared__ unsigned short P[16][1032];   // bf16 unnormalized p; stride 1032
    __shared__ float red_max[4][16];
    __shared__ float red_sum[4][16];

    const int t = threadIdx.x;
    const int lane = t & 63;
    const int wv = t >> 6;
    const int li = lane & 15;
    const int g = lane >> 4;
    const int koff = g * 8;
    const int bh = blockIdx.y;
    const int b = bh / NH, h = bh % NH;
    const int n0 = blockIdx.x * 16;
    const int cb = wv * 256;

    // weight: one f32x4 per lane covers the wave's whole 256-col stripe (shfl-broadcast later)
    f32x4 w4 = *(const f32x4*)(weight + b * NN + cb + lane * 4);

    // ---- q fragment (B-operand): col = li -> n = n0+li, k = koff+j (+32 second k-step)
    const unsigned short* qp = qkvb + (size_t)(b * NN + n0 + li) * TC + h * 64 + koff;
    short8 qf0, qf1;
    gload16(qf0, qp);          // outstanding: 2 (+1 compiler w4 before, harmless: oldest side)
    gload16(qf1, qp + 32);

    const unsigned short* kbase = qkvb + (size_t)(b * NN + cb + li) * TC + 768 + h * 64 + koff;
    const float* mrow = mask + (size_t)b * NN * NN + (size_t)(n0 + li) * NN + cb + g * 4;

    f32x4 acc[16];
    short8 kA[8], kB[8];
    f32x4 mA[4], mB[4];

    auto kissue = [&](int c, short8* kb2, f32x4* mb2) {   // 12 VMEM per chunk
#pragma unroll
        for (int j = 0; j < 4; ++j) {
            const unsigned short* kp = kbase + (size_t)((c * 4 + j) * 16) * TC;
            gload16(kb2[2 * j],     kp);
            gload16(kb2[2 * j + 1], kp + 32);
            gloadf4(mb2[j], mrow + (c * 4 + j) * 16);
        }
    };
    auto kcomp = [&](int c, const short8* kb2, const f32x4* mb2) {
#pragma unroll
        for (int j = 0; j < 4; ++j) {
            f32x4 ci = mb2[j] * 96.0f;     // mask pre-scaled into C-in (scale=1/96 exact)
            ci = __builtin_amdgcn_mfma_f32_16x16x32_bf16(kb2[2 * j],     qf0, ci, 0, 0, 0);
            ci = __builtin_amdgcn_mfma_f32_16x16x32_bf16(kb2[2 * j + 1], qf1, ci, 0, 0, 0);
            acc[c * 4 + j] = ci;
        }
    };

    kissue(0, kA, mA);           // out: qf2 + 12
    kissue(1, kB, mB);           // out: qf2 + 24
    WAITV(12);                   // drains qf + c0 (oldest 14)
    kcomp(0, kA, mA);
    kissue(2, kA, mA);           // out: c1(12) + c2(12)
    WAITV(12);                   // drains c1
    kcomp(1, kB, mB);
    kissue(3, kB, mB);           // out: c2(12) + c3(12)
    WAITV(12);                   // drains c2
    kcomp(2, kA, mA);
    WAITV(0);                    // drains c3
    kcomp(3, kB, mB);

    // ---- row max over this wave's 256 cols (acc = s*96; max scales monotonically)
    const float scale = 1.0f / 96.0f;
    float rmax = -1e30f;
#pragma unroll
    for (int cf = 0; cf < 16; ++cf) {
#pragma unroll
        for (int r = 0; r < 4; ++r) rmax = fmaxf(rmax, acc[cf][r]);
    }
    rmax = fmaxf(rmax, __shfl_xor(rmax, 16, 64));
    rmax = fmaxf(rmax, __shfl_xor(rmax, 32, 64));
    if (lane < 16) red_max[wv][lane] = rmax;
    __syncthreads();
    rmax = fmaxf(fmaxf(red_max[0][li], red_max[1][li]),
                 fmaxf(red_max[2][li], red_max[3][li])) * scale;

    // ---- p = exp(s-max)*w; stage bf16 p into LDS (unnormalized); weighted row sum
    // weight for (cf, g, r): lane cf*4+g holds w4[r] = weight[cb + (cf*4+g)*4 + r]
    float rsum = 0.f;
#pragma unroll
    for (int cf = 0; cf < 16; ++cf) {
        f32x4 wcf;
#pragma unroll
        for (int r = 0; r < 4; ++r) wcf[r] = __shfl(w4[r], cf * 4 + g, 64);
        u16x4 pb;
#pragma unroll
        for (int r = 0; r < 4; ++r) {
            float p = __expf(acc[cf][r] * scale - rmax) * (wcf[r] + 1e-10f);
            acc[cf][r] = p;
            rsum += p;
            pb[r] = f2bf(p);
        }
        *(u16x4*)&P[li][cb + cf * 16 + g * 4] = pb;
    }
    rsum += __shfl_xor(rsum, 16, 64);
    rsum += __shfl_xor(rsum, 32, 64);
    if (lane < 16) red_sum[wv][lane] = rsum;
    __syncthreads();   // covers P writes + red_sum

    // ---- PV: out(16 x 64), wave handles 16 d-cols; counted depth-2 pipeline on V
    f32x4 o = {};
    const unsigned short* vbase = vt + ((size_t)bh * 64 + wv * 16 + li) * NN + koff;
    short8 vA[8], vB[8];
    auto vissue = [&](int c, short8* vb2) {               // 8 VMEM per chunk
#pragma unroll
        for (int j = 0; j < 8; ++j) gload16(vb2[j], vbase + (c * 8 + j) * 32);
    };
    auto vcomp = [&](int c, const short8* vb2) {
#pragma unroll
        for (int j = 0; j < 8; ++j) {
            short8 pa = *(const short8*)&P[li][(c * 8 + j) * 32 + koff];
            o = __builtin_amdgcn_mfma_f32_16x16x32_bf16(pa, vb2[j], o, 0, 0, 0);
        }
    };
    vissue(0, vA);               // out: 8
    vissue(1, vB);               // out: 16
    WAITV(8);                    // v0 done
    vcomp(0, vA);
    vissue(2, vA);               // out: 16
    WAITV(8);                    // v1 done
    vcomp(1, vB);
    vissue(3, vB);               // out: 16
    WAITV(8);                    // v2 done
    vcomp(2, vA);
    WAITV(0);                    // v3 done
    vcomp(3, vB);

    // ---- epilogue: outb (bf16 attn-out for head GEMMs), normalized
    const float rinv = 1.0f / (red_sum[0][li] + red_sum[1][li]
                             + red_sum[2][li] + red_sum[3][li]);
    const int dcol = h * 64 + wv * 16 + li;
#pragma unroll
    for (int r = 0; r < 4; ++r) {
        const int row = g * 4 + r;
        const float rv = 1.0f / (red_sum[0][row] + red_sum[1][row]
                               + red_sum[2][row] + red_sum[3][row]);
        outb[(size_t)(b * NN + n0 + row) * NC + dcol] = f2bf(o[r] * rv);
    }

    // ---- attn f32 store last: fire-and-forget (drained at kernel end)
    float* arow = attn_out + (size_t)bh * NN * NN + (size_t)(n0 + li) * NN + cb + g * 4;
#pragma unroll
    for (int cf = 0; cf < 16; ++cf) {
        f32x4 a4;
#pragma unroll
        for (int r = 0; r < 4; ++r) a4[r] = acc[cf][r] * rinv;
        *(f32x4*)(arow + cf * 16) = a4;
    }
}

// ---------- launch ----------
extern "C" void kernel_launch(void* const* d_in, const int* in_sizes, int n_in,
                              void* d_out, int out_size, void* d_ws, size_t ws_size,
                              hipStream_t stream) {
    const float* x      = (const float*)d_in[0];
    const float* mask   = (const float*)d_in[1];
    const float* weight = (const float*)d_in[2];
    const float* qkv_w  = (const float*)d_in[3];
    const float* mu_w   = (const float*)d_in[4];
    const float* mu_b   = (const float*)d_in[5];
    const float* ls_w   = (const float*)d_in[6];
    const float* ls_b   = (const float*)d_in[7];

    char* ws = (char*)d_ws;
    unsigned short* xb   = (unsigned short*)(ws + OFF_XB);
    unsigned short* wq   = (unsigned short*)(ws + OFF_WQ);
    unsigned short* wmu  = (unsigned short*)(ws + OFF_WMU);
    unsigned short* wls  = (unsigned short*)(ws + OFF_WLS);
    unsigned short* qkvb = (unsigned short*)(ws + OFF_QKVB);
    unsigned short* vt   = (unsigned short*)(ws + OFF_VT);
    unsigned short* outb = (unsigned short*)(ws + OFF_OUTB);

    float* out_mu   = (float*)d_out;                 // (4,1024,768)
    float* out_ls   = out_mu + 3145728;              // (4,1024,768)
    float* out_attn = out_mu + 6291456;              // (4,12,1024,1024)

    // one fused cast: 1376256 float4s / 256 = 5376 blocks
    cast_all<<<5376, 256, 0, stream>>>(x, qkv_w, mu_w, ls_w, xb);

    gemm_qkv<<<dim3(TC / 128, 4096 / 128), 256, 0, stream>>>(xb, wq, qkvb);

    transpose_v<<<dim3(NN / 64, NB * NH), 256, 0, stream>>>(qkvb, vt);

    attn_kernel<<<dim3(NN / 16, NB * NH), 256, 0, stream>>>(
        qkvb, vt, mask, weight, out_attn, outb);

    gemm_heads<<<dim3(NC / 128, 4096 / 128, 2), 256, 0, stream>>>(
        outb, wmu, wls, mu_b, ls_b, out_mu, out_ls);
}

// Round 5
// 161.487 us; speedup vs baseline: 1.1875x; 1.1769x over previous
//
#include <hip/hip_runtime.h>
#include <hip/hip_bf16.h>

// ---------- types ----------
typedef __attribute__((ext_vector_type(8))) short short8;      // 8 x bf16 (4 VGPR) MFMA frag
typedef __attribute__((ext_vector_type(4))) float f32x4;       // MFMA accumulator
typedef __attribute__((ext_vector_type(4))) unsigned short u16x4;

// ---------- constants ----------
// B=4, N=1024, C=768, H=12, Dh=64, 3C=2304, scale=(C*H)^-0.5 = 1/96 (96^2 = 9216 = C*H)
#define NB 4
#define NN 1024
#define NC 768
#define NH 12
#define TC 2304

// workspace byte offsets (kp reuses xb region: xb dead after gemm_qkv)
#define OFF_XB   0ul                       // x bf16 -> later kp   6291456
#define OFF_WQ   6291456ul                 // qkv_w bf16      2304*768*2  = 3538944
#define OFF_WMU  (OFF_WQ + 3538944ul)      // mu_w bf16       768*384*2   = 589824
#define OFF_WLS  (OFF_WMU + 589824ul)      // ls_w bf16
#define OFF_QKVB (OFF_WLS + 589824ul)      // qkv bf16        4096*2304*2 = 18874368
#define OFF_V3   (OFF_QKVB + 18874368ul)   // v frag-packed   48*1024*64*2= 6291456
#define OFF_OUTB (OFF_V3 + 6291456ul)      // attn-out bf16   4096*768*2  = 6291456

__device__ __forceinline__ unsigned short f2bf(float f) {
    unsigned int u = __float_as_uint(f);
    u = (u + 0x7FFFu + ((u >> 16) & 1u)) >> 16;
    return (unsigned short)u;
}

__device__ __forceinline__ void gload_lds16(const unsigned short* g, unsigned short* l) {
    __builtin_amdgcn_global_load_lds(
        (const __attribute__((address_space(1))) unsigned int*)g,
        (__attribute__((address_space(3))) unsigned int*)l, 16, 0, 0);
}

// inline-asm loads: volatile -> fixed issue order in the vmcnt FIFO
__device__ __forceinline__ void gload16(short8& dst, const unsigned short* p) {
    asm volatile("global_load_dwordx4 %0, %1, off" : "=v"(dst) : "v"(p));
}
__device__ __forceinline__ void gloadf4(f32x4& dst, const float* p) {
    asm volatile("global_load_dwordx4 %0, %1, off" : "=v"(dst) : "v"(p));
}
#define WAITV(N) do { asm volatile("s_waitcnt vmcnt(" #N ")" ::: "memory"); \
                      __builtin_amdgcn_sched_barrier(0); } while (0)
#define SBAR()   __builtin_amdgcn_sched_barrier(0)

// ---------- fused cast f32 -> bf16 ----------
__global__ void cast_all(const float* __restrict__ x, const float* __restrict__ qkv_w,
                         const float* __restrict__ mu_w, const float* __restrict__ ls_w,
                         unsigned short* __restrict__ dst) {
    int i = blockIdx.x * blockDim.x + threadIdx.x;   // float4 index
    const float* src; int off;
    if (i < 786432)            { src = x;     off = i; }
    else if (i < 1228800)      { src = qkv_w; off = i - 786432; }
    else if (i < 1302528)      { src = mu_w;  off = i - 1228800; }
    else                       { src = ls_w;  off = i - 1302528; }
    f32x4 v = ((const f32x4*)src)[off];
    u16x4 o;
#pragma unroll
    for (int j = 0; j < 4; ++j) o[j] = f2bf(v[j]);
    ((u16x4*)dst)[i] = o;
}

// ---------- shared GEMM body (unchanged, validated) ----------
template <int EPI>
__device__ __forceinline__ void gemm_body(
    unsigned short* As, unsigned short* Bs,
    const unsigned short* __restrict__ A, const unsigned short* __restrict__ Bm,
    int K, int lda, int ldb, void* __restrict__ Cout, int ldc,
    const float* __restrict__ bias, int row0, int col0)
{
    const int t = threadIdx.x;
    const int lane = t & 63;
    const int wv = t >> 6;
    const int wm = wv >> 1, wn = wv & 1;
    const int li = lane & 15;
    const int koff = (lane >> 4) * 8;

    f32x4 acc[4][4] = {};

    const int tr = t >> 2;
    const int tc = (t & 3) * 8;
    const unsigned short* ag = A + (size_t)(row0 + tr) * lda + tc;
    const unsigned short* bg = Bm + (size_t)(col0 + tr) * ldb + tc;

    for (int kt = 0; kt < K; kt += 32) {
        gload_lds16(ag,            As + t * 8);
        gload_lds16(ag + 64 * lda, As + 2048 + t * 8);
        gload_lds16(bg,            Bs + t * 8);
        gload_lds16(bg + 64 * ldb, Bs + 2048 + t * 8);
        ag += 32; bg += 32;
        __syncthreads();
        short8 af[4], bf[4];
#pragma unroll
        for (int m = 0; m < 4; ++m)
            af[m] = *(const short8*)&As[(wm * 64 + m * 16 + li) * 32 + koff];
#pragma unroll
        for (int n = 0; n < 4; ++n)
            bf[n] = *(const short8*)&Bs[(wn * 64 + n * 16 + li) * 32 + koff];
#pragma unroll
        for (int m = 0; m < 4; ++m)
#pragma unroll
            for (int n = 0; n < 4; ++n)
                acc[m][n] = __builtin_amdgcn_mfma_f32_16x16x32_bf16(af[m], bf[n], acc[m][n], 0, 0, 0);
        __syncthreads();
    }

#pragma unroll
    for (int m = 0; m < 4; ++m) {
        const int row = row0 + wm * 64 + m * 16 + (lane >> 4) * 4;
#pragma unroll
        for (int n = 0; n < 4; ++n) {
            const int col = col0 + wn * 64 + n * 16 + li;
#pragma unroll
            for (int r = 0; r < 4; ++r) {
                if (EPI == 0) {
                    ((unsigned short*)Cout)[(size_t)(row + r) * ldc + col] = f2bf(acc[m][n][r]);
                } else {
                    ((float*)Cout)[(size_t)(row + r) * ldc + col] = acc[m][n][r] + bias[col];
                }
            }
        }
    }
}

__global__ __launch_bounds__(256, 2) void gemm_qkv(
    const unsigned short* __restrict__ A, const unsigned short* __restrict__ Bm,
    unsigned short* __restrict__ C)
{
    __shared__ unsigned short As[128 * 32];
    __shared__ unsigned short Bs[128 * 32];
    const int bid = blockIdx.y * gridDim.x + blockIdx.x;
    const int nwg = gridDim.x * gridDim.y;
    const int swz = (bid & 7) * (nwg >> 3) + (bid >> 3);
    const int row0 = (swz / gridDim.x) * 128;
    const int col0 = (swz % gridDim.x) * 128;
    gemm_body<0>(As, Bs, A, Bm, NC, NC, NC, C, TC, nullptr, row0, col0);
}

__global__ __launch_bounds__(256, 2) void gemm_heads(
    const unsigned short* __restrict__ outb,
    const unsigned short* __restrict__ wmu, const unsigned short* __restrict__ wls,
    const float* __restrict__ mu_b, const float* __restrict__ ls_b,
    float* __restrict__ out_mu, float* __restrict__ out_ls)
{
    __shared__ unsigned short As[128 * 32];
    __shared__ unsigned short Bs[128 * 32];
    const int bid = blockIdx.y * gridDim.x + blockIdx.x;
    const int nwg = gridDim.x * gridDim.y;
    const int swz = (bid & 7) * (nwg >> 3) + (bid >> 3);
    const int row0 = (swz / gridDim.x) * 128;
    const int col0 = (swz % gridDim.x) * 128;
    const int z = blockIdx.z;
    gemm_body<1>(As, Bs, outb + (z ? 384 : 0), z ? wls : wmu, 384, NC, 384,
                 z ? (void*)out_ls : (void*)out_mu, NC, z ? ls_b : mu_b, row0, col0);
}

// ---------- pack K (swizzled per-head rows) + V (frag-order) ----------
// kp[bh][m][128B row], byte-slot d*2 XOR ((m&7)<<4)   (T2 pre-swizzle for gload_lds)
// v3[bh][kt=m/32][d][m%32]  -> attn PV loads are contiguous 1KB per wave-instr
__global__ __launch_bounds__(256, 4) void pack_kv(
    const unsigned short* __restrict__ qkvb, unsigned short* __restrict__ kp,
    unsigned short* __restrict__ v3)
{
    __shared__ unsigned short tile[64][65];
    const int t = threadIdx.x;
    const int bh = blockIdx.y;
    const int b = bh / NH, h = bh % NH;
    const int m0 = blockIdx.x * 64;
    // K: direct repack (d stays inner; swizzle the 16B slot)
#pragma unroll
    for (int i = 0; i < 2; ++i) {
        int lin = i * 256 + t;
        int mr = lin >> 3;                 // 0..63
        int dr = (lin & 7) * 8;            // shorts
        short8 v = *(const short8*)(qkvb + (size_t)(b * NN + m0 + mr) * TC + 768 + h * 64 + dr);
        int dbyte = (dr * 2) ^ ((mr & 7) << 4);
        *(short8*)(kp + (size_t)(bh * NN + m0 + mr) * 64 + (dbyte >> 1)) = v;
    }
    // V: LDS transpose then frag-order write
#pragma unroll
    for (int i = 0; i < 2; ++i) {
        int lin = i * 256 + t;
        int mr = lin >> 3;
        int dr = (lin & 7) * 8;
        short8 v = *(const short8*)(qkvb + (size_t)(b * NN + m0 + mr) * TC + 1536 + h * 64 + dr);
#pragma unroll
        for (int j = 0; j < 8; ++j) tile[mr][dr + j] = (unsigned short)v[j];
    }
    __syncthreads();
#pragma unroll
    for (int i = 0; i < 2; ++i) {
        int lin = i * 256 + t;
        int dw = lin >> 3;                 // 0..63
        int mw = (lin & 7) * 8;            // 0..56
        short8 v;
#pragma unroll
        for (int j = 0; j < 8; ++j) v[j] = (short)tile[mw + j][dw];
        int kt = (m0 + mw) >> 5;
        int mm = mw & 31;
        *(short8*)(v3 + ((size_t)(bh * 32 + kt) * 64 + dw) * 32 + mm) = v;
    }
}

// ---------- fused attention: K via per-wave gload_lds chunks, V via frag-packed reg loads ----------
// grid (N/16, B*H); block 256 = 4 waves; wave wv owns key cols [wv*256, wv*256+256).
__global__ __launch_bounds__(256, 3) void attn_kernel(
    const unsigned short* __restrict__ qkvb, const unsigned short* __restrict__ kp,
    const unsigned short* __restrict__ v3, const float* __restrict__ mask,
    const float* __restrict__ weight, float* __restrict__ attn_out,
    unsigned short* __restrict__ outb)
{
    __shared__ char smem[33024];           // kstage 4 waves x 2 bufs x 4KB | later P[16][1032]
    __shared__ float red_max[4][16];
    __shared__ float red_sum[4][16];

    const int t = threadIdx.x;
    const int lane = t & 63;
    const int wv = t >> 6;
    const int li = lane & 15;
    const int g = lane >> 4;
    const int koff = g * 8;
    const int bh = blockIdx.y;
    const int b = bh / NH, h = bh % NH;
    const int n0 = blockIdx.x * 16;
    const int cb = wv * 256;

    unsigned short* kw = (unsigned short*)smem + wv * 4096;   // 2 x 2048 shorts
    const unsigned short* kps = kp + (size_t)bh * 65536 + cb * 64;
    const float* mrow = mask + (size_t)b * NN * NN + (size_t)(n0 + li) * NN + cb + g * 4;

    // ---- prologue: weight (1 f32x4/lane, coalesced), q frags, first two K chunks
    f32x4 w4;
    gloadf4(w4, weight + b * NN + cb + lane * 4);
    const unsigned short* qp = qkvb + (size_t)(b * NN + n0 + li) * TC + h * 64 + koff;
    short8 qf0, qf1;
    gload16(qf0, qp);
    gload16(qf1, qp + 32);

    f32x4 acc[16];
    f32x4 mk[2][2];

    // stage chunk c (32 keys, 4KB) + its 2 mask f32x4s: 6 VMEM ops
#define KISSUE(c) do {                                                        \
        const unsigned short* ks_ = kps + (c) * 2048;                         \
        unsigned short* kd_ = kw + ((c) & 1) * 2048;                          \
        gload_lds16(ks_ + 0 * 512 + lane * 8, kd_ + 0 * 512 + lane * 8);      \
        gload_lds16(ks_ + 1 * 512 + lane * 8, kd_ + 1 * 512 + lane * 8);      \
        gload_lds16(ks_ + 2 * 512 + lane * 8, kd_ + 2 * 512 + lane * 8);      \
        gload_lds16(ks_ + 3 * 512 + lane * 8, kd_ + 3 * 512 + lane * 8);      \
        gloadf4(mk[(c) & 1][0], mrow + ((c) * 2 + 0) * 16);                   \
        gloadf4(mk[(c) & 1][1], mrow + ((c) * 2 + 1) * 16);                   \
    } while (0)

    // compute chunk c: 2 cf (16 keys each), swizzled ds_read_b128 frags, mask as C-in
#define KSTEP(c) do {                                                         \
        const unsigned short* kb_ = kw + ((c) & 1) * 2048;                    \
        const int swz_ = (li & 7) << 4;                                       \
        _Pragma("unroll")                                                     \
        for (int s = 0; s < 2; ++s) {                                         \
            const int keyb_ = (s * 16 + li) * 64;                             \
            short8 kf0 = *(const short8*)&kb_[keyb_ + (((g * 16) ^ swz_) >> 1)];        \
            short8 kf1 = *(const short8*)&kb_[keyb_ + (((64 + g * 16) ^ swz_) >> 1)];   \
            f32x4 ci = mk[(c) & 1][s] * 96.0f;                                \
            ci = __builtin_amdgcn_mfma_f32_16x16x32_bf16(kf0, qf0, ci, 0, 0, 0); \
            ci = __builtin_amdgcn_mfma_f32_16x16x32_bf16(kf1, qf1, ci, 0, 0, 0); \
            acc[(c) * 2 + s] = ci;                                            \
        }                                                                     \
    } while (0)

    KISSUE(0); KISSUE(1);
    WAITV(6);  KSTEP(0); SBAR(); KISSUE(2);
    WAITV(6);  KSTEP(1); SBAR(); KISSUE(3);
    WAITV(6);  KSTEP(2); SBAR(); KISSUE(4);
    WAITV(6);  KSTEP(3); SBAR(); KISSUE(5);
    WAITV(6);  KSTEP(4); SBAR(); KISSUE(6);
    WAITV(6);  KSTEP(5); SBAR(); KISSUE(7);
    WAITV(6);  KSTEP(6);
    WAITV(0);  KSTEP(7);
#undef KISSUE
#undef KSTEP

    // ---- row max (acc = s*96; monotone)
    const float scale = 1.0f / 96.0f;
    float rmax = -1e30f;
#pragma unroll
    for (int cf = 0; cf < 16; ++cf) {
#pragma unroll
        for (int r = 0; r < 4; ++r) rmax = fmaxf(rmax, acc[cf][r]);
    }
    rmax = fmaxf(rmax, __shfl_xor(rmax, 16, 64));
    rmax = fmaxf(rmax, __shfl_xor(rmax, 32, 64));
    if (lane < 16) red_max[wv][lane] = rmax;
    __syncthreads();                       // also: all waves done with kstage LDS
    rmax = fmaxf(fmaxf(red_max[0][li], red_max[1][li]),
                 fmaxf(red_max[2][li], red_max[3][li])) * scale;

    // ---- p = exp(s-max)*w; stage bf16 p into LDS (overlays kstage); weighted row sum
    unsigned short (*P)[1032] = (unsigned short(*)[1032])smem;
    float rsum = 0.f;
#pragma unroll
    for (int cf = 0; cf < 16; ++cf) {
        f32x4 wcf;
#pragma unroll
        for (int r = 0; r < 4; ++r) wcf[r] = __shfl(w4[r], cf * 4 + g, 64);
        u16x4 pb;
#pragma unroll
        for (int r = 0; r < 4; ++r) {
            float p = __expf(acc[cf][r] * scale - rmax) * (wcf[r] + 1e-10f);
            acc[cf][r] = p;
            rsum += p;
            pb[r] = f2bf(p);
        }
        *(u16x4*)&P[li][cb + cf * 16 + g * 4] = pb;
    }
    rsum += __shfl_xor(rsum, 16, 64);
    rsum += __shfl_xor(rsum, 32, 64);
    if (lane < 16) red_sum[wv][lane] = rsum;
    __syncthreads();                       // covers P writes + red_sum

    // ---- PV: frag-packed V, depth-2 register pipeline (SSA-safe), counted waits
    f32x4 o = {};
    const unsigned short* v3s = v3 + (size_t)bh * 65536 + wv * 512 + li * 32 + g * 8;
    short8 vA[8], vB[8];
#define VISSUE(c, vb2) do {                                                   \
        _Pragma("unroll")                                                     \
        for (int j = 0; j < 8; ++j) gload16(vb2[j], v3s + ((c) * 8 + j) * 2048); \
    } while (0)
#define VCOMP(c, vb2) do {                                                    \
        _Pragma("unroll")                                                     \
        for (int j = 0; j < 8; ++j) {                                         \
            short8 pa = *(const short8*)&P[li][((c) * 8 + j) * 32 + koff];    \
            o = __builtin_amdgcn_mfma_f32_16x16x32_bf16(pa, vb2[j], o, 0, 0, 0); \
        }                                                                     \
    } while (0)
    VISSUE(0, vA);
    VISSUE(1, vB);
    WAITV(8);  VCOMP(0, vA); SBAR(); VISSUE(2, vA);
    WAITV(8);  VCOMP(1, vB); SBAR(); VISSUE(3, vB);
    WAITV(8);  VCOMP(2, vA);
    WAITV(0);  VCOMP(3, vB);
#undef VISSUE
#undef VCOMP

    // ---- epilogue: outb (bf16, normalized) then attn f32 stores (fire-and-forget)
    const float rinv = 1.0f / (red_sum[0][li] + red_sum[1][li]
                             + red_sum[2][li] + red_sum[3][li]);
    const int dcol = h * 64 + wv * 16 + li;
#pragma unroll
    for (int r = 0; r < 4; ++r) {
        const int row = g * 4 + r;
        const float rv = 1.0f / (red_sum[0][row] + red_sum[1][row]
                               + red_sum[2][row] + red_sum[3][row]);
        outb[(size_t)(b * NN + n0 + row) * NC + dcol] = f2bf(o[r] * rv);
    }

    float* arow = attn_out + (size_t)bh * NN * NN + (size_t)(n0 + li) * NN + cb + g * 4;
#pragma unroll
    for (int cf = 0; cf < 16; ++cf) {
        f32x4 a4;
#pragma unroll
        for (int r = 0; r < 4; ++r) a4[r] = acc[cf][r] * rinv;
        *(f32x4*)(arow + cf * 16) = a4;
    }
}

// ---------- launch ----------
extern "C" void kernel_launch(void* const* d_in, const int* in_sizes, int n_in,
                              void* d_out, int out_size, void* d_ws, size_t ws_size,
                              hipStream_t stream) {
    const float* x      = (const float*)d_in[0];
    const float* mask   = (const float*)d_in[1];
    const float* weight = (const float*)d_in[2];
    const float* qkv_w  = (const float*)d_in[3];
    const float* mu_w   = (const float*)d_in[4];
    const float* mu_b   = (const float*)d_in[5];
    const float* ls_w   = (const float*)d_in[6];
    const float* ls_b   = (const float*)d_in[7];

    char* ws = (char*)d_ws;
    unsigned short* xb   = (unsigned short*)(ws + OFF_XB);   // becomes kp after gemm_qkv
    unsigned short* kp   = (unsigned short*)(ws + OFF_XB);
    unsigned short* wq   = (unsigned short*)(ws + OFF_WQ);
    unsigned short* wmu  = (unsigned short*)(ws + OFF_WMU);
    unsigned short* wls  = (unsigned short*)(ws + OFF_WLS);
    unsigned short* qkvb = (unsigned short*)(ws + OFF_QKVB);
    unsigned short* v3   = (unsigned short*)(ws + OFF_V3);
    unsigned short* outb = (unsigned short*)(ws + OFF_OUTB);

    float* out_mu   = (float*)d_out;                 // (4,1024,768)
    float* out_ls   = out_mu + 3145728;              // (4,1024,768)
    float* out_attn = out_mu + 6291456;              // (4,12,1024,1024)

    cast_all<<<5376, 256, 0, stream>>>(x, qkv_w, mu_w, ls_w, xb);

    gemm_qkv<<<dim3(TC / 128, 4096 / 128), 256, 0, stream>>>(xb, wq, qkvb);

    pack_kv<<<dim3(NN / 64, NB * NH), 256, 0, stream>>>(qkvb, kp, v3);

    attn_kernel<<<dim3(NN / 16, NB * NH), 256, 0, stream>>>(
        qkvb, kp, v3, mask, weight, out_attn, outb);

    gemm_heads<<<dim3(NC / 128, 4096 / 128, 2), 256, 0, stream>>>(
        outb, wmu, wls, mu_b, ls_b, out_mu, out_ls);
}